// Round 5
// baseline (729.264 us; speedup 1.0000x reference)
//
#include <hip/hip_runtime.h>
#include <math.h>

#define NN 1024
#define NNP 1025
#define DD 256
#define CC 5
#define G3 768
#define MAXT 512
#define NA 70

typedef _Float16 v8h __attribute__((ext_vector_type(8)));
typedef float v4f __attribute__((ext_vector_type(4)));

__device__ __forceinline__ int scale_of(int a){ return (a<15)?0:((a<55)?1:2); }
__device__ __forceinline__ int off_of(int s){ return (s==0)?0:((s==1)?15:55); }

__device__ __forceinline__ float sigf(float x){ return __fdividef(1.f, 1.f + __expf(-x)); }
__device__ __forceinline__ float tanhf_fast(float x){ return 1.f - __fdividef(2.f, __expf(2.f*x) + 1.f); }

// LDS-only barrier: drain lgkmcnt but leave global loads (vmcnt) in flight.
__device__ __forceinline__ void lds_barrier(){
  asm volatile("s_waitcnt lgkmcnt(0)" ::: "memory");
  __builtin_amdgcn_s_barrier();
  asm volatile("" ::: "memory");
}

// K0: tpos = time_positions * audio_len ; abn = softmax(node_pred)[:,0]
__global__ void prep_kernel(const float* __restrict__ tp_in, const float* __restrict__ node_pred,
                            const float* __restrict__ audio_len,
                            float* __restrict__ tpos, float* __restrict__ abn){
  int i = blockIdx.x*blockDim.x + threadIdx.x;
  if (i >= NN) return;
  tpos[i] = tp_in[i]*audio_len[0];
  float pv[CC]; float m = -1e30f;
  for (int c=0;c<CC;++c){ pv[c]=node_pred[i*CC+c]; m=fmaxf(m,pv[c]); }
  float s=0.f;
  for (int c=0;c<CC;++c) s += expf(pv[c]-m);
  abn[i] = expf(pv[0]-m)/s;
}

// K1: per-anchor stable gather of masked node indices + counts (ballot prefix)
__global__ void order_kernel(const float* __restrict__ tpos, const float* __restrict__ anchors,
                             int* __restrict__ order, int* __restrict__ cnteff){
  int a = blockIdx.x; int lane = threadIdx.x; // 64 threads = 1 wave
  float s = anchors[2*a], e = anchors[2*a+1];
  int* ord = order + a*MAXT;
  int cnt = 0;
  for (int base=0; base<NN; base+=64){
    float tp = tpos[base+lane];
    bool msk = (tp>=s)&&(tp<=e);
    unsigned long long bal = __ballot(msk);
    int off = (int)__popcll(bal & ((1ull<<lane)-1ull));
    if (msk && (cnt+off)<MAXT) ord[cnt+off] = base+lane;
    cnt += (int)__popcll(bal);
  }
  if (lane==0){ int c = cnt<MAXT?cnt:MAXT; cnteff[2*a]=c; cnteff[2*a+1]=(c>0)?c:1; }
}

// K2: pack whh into MFMA B-fragments grouped per-wave as 6 col-tiles:
// nt0,1 = r cols [w*32+0..15],[+16..31]; nt2,3 = z; nt4,5 = n.
__global__ void pack_whhB(const float* __restrict__ whh, uint4* __restrict__ dst){
  int i = blockIdx.x*256 + threadIdx.x;
  if (i >= 6*8*64*48) return;
  int q    = i & 7;
  int nt   = (i>>3) % 6;
  int lane = (i/48) & 63;
  int wv   = (i/3072) & 7;
  int sd   = i/24576;
  int gt = nt>>1, half = nt&1;
  int j = gt*256 + wv*32 + half*16 + (lane&15);
  int kbase = 32*q + 8*(lane>>4);
  const float* src = whh + ((size_t)sd*G3 + j)*DD + kbase;
  unsigned int u[4];
  #pragma unroll
  for (int rp=0;rp<4;++rp){
    _Float16 a = (_Float16)src[2*rp];
    _Float16 b = (_Float16)src[2*rp+1];
    unsigned short ua = __builtin_bit_cast(unsigned short, a);
    unsigned short ub = __builtin_bit_cast(unsigned short, b);
    u[rp] = (unsigned int)ua | ((unsigned int)ub<<16);
  }
  uint4 v; v.x=u[0]; v.y=u[1]; v.z=u[2]; v.w=u[3];
  dst[i] = v;
}

// K3: E_perm[sd][node][w][cl][slot] = emb.wih^T + bih (+bhh for r,z slots)
__global__ __launch_bounds__(256) void e_gemm(const float* __restrict__ emb, const float* __restrict__ wih,
                       const float* __restrict__ bih, const float* __restrict__ bhh,
                       float* __restrict__ E){
  int sd = blockIdx.z;
  int row0 = blockIdx.x*64, col0 = blockIdx.y*64;
  const float* W = wih + (size_t)sd*G3*DD;
  __shared__ float As[64][65];
  __shared__ float Bs[64][65];
  int tid = threadIdx.x;
  int tr = tid>>4, tc = tid&15;
  float acc[4][4] = {};
  for (int kb=0; kb<4; ++kb){
    for (int i=0;i<4;++i){
      int e4 = i*256 + tid;
      int rr = e4>>4, qq = e4&15;
      float4 av = reinterpret_cast<const float4*>(emb)[ (size_t)(row0+rr)*64 + kb*16 + qq ];
      As[rr][qq*4+0]=av.x; As[rr][qq*4+1]=av.y; As[rr][qq*4+2]=av.z; As[rr][qq*4+3]=av.w;
      float4 bv = reinterpret_cast<const float4*>(W)[ (size_t)(col0+rr)*64 + kb*16 + qq ];
      Bs[rr][qq*4+0]=bv.x; Bs[rr][qq*4+1]=bv.y; Bs[rr][qq*4+2]=bv.z; Bs[rr][qq*4+3]=bv.w;
    }
    __syncthreads();
    for (int k=0;k<64;++k){
      float a0[4], b0[4];
      #pragma unroll
      for (int i=0;i<4;++i) a0[i]=As[tr*4+i][k];
      #pragma unroll
      for (int j=0;j<4;++j) b0[j]=Bs[tc*4+j][k];
      #pragma unroll
      for (int i=0;i<4;++i)
        #pragma unroll
        for (int j=0;j<4;++j)
          acc[i][j] += a0[i]*b0[j];
    }
    __syncthreads();
  }
  for (int i=0;i<4;++i){
    int row = row0 + tr*4 + i;
    for (int j=0;j<4;++j){
      int col = col0 + tc*4 + j;
      int gt = col>>8; int c = col&255;
      int wv = c>>5; int mm = c&31; int half = mm>>4; int cl = mm&15;
      int slot = half*3 + gt;
      float val = acc[i][j] + bih[sd*G3+col] + ((gt<2)? bhh[sd*G3+col] : 0.f);
      E[(((size_t)sd*NNP + row)*8 + wv)*128 + cl*8 + slot] = val;
    }
  }
}

// K3b: fake node row NN = pure bias (used for masked steps / cnt==0)
__global__ void fill_bias(const float* __restrict__ bih, const float* __restrict__ bhh,
                          float* __restrict__ E){
  int i = blockIdx.x*256 + threadIdx.x;   // 6*8*16*6 = 4608
  if (i >= 6*8*16*6) return;
  int slot = i % 6; int cl = (i/6)&15; int wv = (i/96)&7; int sd = i/768;
  int half = slot/3, gt = slot%3;
  int j = gt*256 + wv*32 + half*16 + cl;
  float v = bih[sd*G3+j] + ((gt<2)? bhh[sd*G3+j] : 0.f);
  E[(((size_t)sd*NNP + NN)*8 + wv)*128 + cl*8 + slot] = v;
}

// K4: per-matrix absmax -> quant scale (9 matrices)
__global__ void absmax_kernel(const float* __restrict__ w1, const float* __restrict__ w2,
                              const float* __restrict__ w30, const float* __restrict__ w31,
                              const float* __restrict__ w32, float* __restrict__ qs){
  int m = blockIdx.x, tid = threadIdx.x;
  const float* p; int n;
  if (m<3){ p = w1 + (size_t)m*256*519; n = 256*519; }
  else if (m<6){ p = w2 + (size_t)(m-3)*256*256; n = 256*256; }
  else { p = (m==6)?w30:((m==7)?w31:w32); n = ((m==7)?125:165)*256; }
  float mx = 0.f;
  for (int i=tid;i<n;i+=256) mx = fmaxf(mx, fabsf(p[i]));
  __shared__ float red[256];
  red[tid]=mx; __syncthreads();
  for (int sft=128; sft>0; sft>>=1){ if (tid<sft) red[tid]=fmaxf(red[tid],red[tid+sft]); __syncthreads(); }
  if (tid==0) qs[m] = fmaxf(red[0]/127.f, 1e-8f);
}

// K5: sequential GRU. One block per (anchor, direction); 8 waves x 96 gates.
// Lane-local nonlinearity; one LDS-only barrier per step (vmcnt never drained);
// E rows prefetched 2 steps ahead in registers.
__global__ __launch_bounds__(512, 2) void gru_kernel(
                           const float* __restrict__ E, const uint4* __restrict__ whhB,
                           const float* __restrict__ bhh,
                           const int* __restrict__ order, const int* __restrict__ cnteff,
                           float* __restrict__ hout){
  int a = blockIdx.x>>1, d = blockIdx.x&1;
  int si = scale_of(a);
  int sd = si*2+d;
  int tid = threadIdx.x;
  int w = tid>>6, lane = tid&63;
  int l15 = lane&15, g16 = lane>>4;

  __shared__ int ord_s[MAXT];
  __shared__ alignas(16) _Float16 h16[2][DD];

  ord_s[tid] = order[a*MAXT + tid];
  if (tid < DD) h16[0][tid] = (_Float16)0.f;

  int cnt = cnteff[2*a], eff = cnteff[2*a+1];

  int c0 = w*32 + l15, c1 = c0 + 16;
  float bn0 = bhh[sd*G3 + 2*DD + c0];
  float bn1 = bhh[sd*G3 + 2*DD + c1];

  // B fragments: 48 x uint4 = 192 dwords resident
  v8h bf[6][8];
  {
    const uint4* wp = whhB + (((size_t)sd*8 + w)*64 + lane)*48;
    #pragma unroll
    for (int nt=0;nt<6;++nt)
      #pragma unroll
      for (int q=0;q<8;++q)
        bf[nt][q] = __builtin_bit_cast(v8h, wp[nt*8+q]);
  }

  const float4* Eb = reinterpret_cast<const float4*>(E) + (size_t)sd*NNP*256;
  int lidx = (w*16 + l15)*2;

  lds_barrier();

  float h0 = 0.f, h1 = 0.f;
  // 2-deep register prefetch: slot[t&1] holds the E row for step t at its use.
  float4 gaA, gbA, gaB, gbB;
  {
    int idx0 = d ? (eff-1) : 0;
    int n0 = (idx0 < cnt) ? ord_s[idx0] : NN;
    const float4* p = Eb + (size_t)n0*256 + lidx;
    gaA = p[0]; gbA = p[1];
  }
  if (eff > 1){
    int idx1 = d ? (eff-2) : 1;
    int n1 = (idx1 < cnt) ? ord_s[idx1] : NN;
    const float4* p = Eb + (size_t)n1*256 + lidx;
    gaB = p[0]; gbB = p[1];
  }

  for (int t=0;t<eff;++t){
    int p = t & 1;
    v4f acc0={0.f,0.f,0.f,0.f}, acc1={0.f,0.f,0.f,0.f};
    v4f acc2={0.f,0.f,0.f,0.f}, acc3={0.f,0.f,0.f,0.f};
    v4f acc4={bn0,bn0,bn0,bn0}, acc5={bn1,bn1,bn1,bn1};
    #pragma unroll
    for (int q=0;q<8;++q){
      v8h af = *reinterpret_cast<const v8h*>(&h16[p][32*q + 8*g16]);
      acc0 = __builtin_amdgcn_mfma_f32_16x16x32_f16(af, bf[0][q], acc0, 0,0,0);
      acc1 = __builtin_amdgcn_mfma_f32_16x16x32_f16(af, bf[1][q], acc1, 0,0,0);
      acc2 = __builtin_amdgcn_mfma_f32_16x16x32_f16(af, bf[2][q], acc2, 0,0,0);
      acc3 = __builtin_amdgcn_mfma_f32_16x16x32_f16(af, bf[3][q], acc3, 0,0,0);
      acc4 = __builtin_amdgcn_mfma_f32_16x16x32_f16(af, bf[4][q], acc4, 0,0,0);
      acc5 = __builtin_amdgcn_mfma_f32_16x16x32_f16(af, bf[5][q], acc5, 0,0,0);
    }
    // consume this step's prefetched row, then reuse the slot for t+2
    float4 fa, fb;
    if (p==0){ fa = gaA; fb = gbA; } else { fa = gaB; fb = gbB; }
    if (t+2 < eff){
      int idx2 = d ? (eff-3-t) : (t+2);
      int n2 = (idx2 < cnt) ? ord_s[idx2] : NN;
      const float4* pp = Eb + (size_t)n2*256 + lidx;
      if (p==0){ gaA = pp[0]; gbA = pp[1]; } else { gaB = pp[0]; gbB = pp[1]; }
    }
    // lane-local GRU cell for columns c0, c1
    float r0 = sigf(fa.x + acc0[0]);
    float z0 = sigf(fa.y + acc2[0]);
    float n0v = tanhf_fast(fa.z + r0*acc4[0]);
    h0 = z0*(h0 - n0v) + n0v;
    float r1 = sigf(fa.w + acc1[0]);
    float z1 = sigf(fb.x + acc3[0]);
    float n1v = tanhf_fast(fb.y + r1*acc5[0]);
    h1 = z1*(h1 - n1v) + n1v;
    if (g16 == 0)      h16[p^1][c0] = (_Float16)h0;
    else if (g16 == 1) h16[p^1][c1] = (_Float16)h1;
    lds_barrier();
  }
  if (g16 == 0)      hout[(size_t)(2*a+d)*DD + c0] = h0;
  else if (g16 == 1) hout[(size_t)(2*a+d)*DD + c1] = h1;
}

// K6: per-anchor MLP (int8 fake-quant on the fly) + softmax-weighted refinement head
__global__ __launch_bounds__(256) void mlp_kernel(const float* __restrict__ hout, const float* __restrict__ abn,
                           const float* __restrict__ anchors, const float* __restrict__ audio_len,
                           const float* __restrict__ w1, const float* __restrict__ w2,
                           const float* __restrict__ w30, const float* __restrict__ w31, const float* __restrict__ w32,
                           const float* __restrict__ sw0, const float* __restrict__ ew0,
                           const float* __restrict__ sw1, const float* __restrict__ ew1,
                           const float* __restrict__ sw2, const float* __restrict__ ew2,
                           const float* __restrict__ qs, float* __restrict__ out){
  int a = blockIdx.x, tid = threadIdx.x;
  int si = scale_of(a);
  int il = a - off_of(si);
  float s = anchors[2*a], e = anchors[2*a+1];
  float al = audio_len[0];
  __shared__ float feat[520];
  __shared__ float h1[256], h2[256], o[168];
  feat[tid]    = hout[(size_t)(2*a+0)*DD + tid];
  feat[DD+tid] = hout[(size_t)(2*a+1)*DD + tid];
  if (tid==0){
    feat[512]=abn[il];
    feat[513]=(s+e)*0.5f/al;
    feat[514]=(e-s)/al;
    feat[515]=0.f; feat[516]=0.f; feat[517]=0.f; feat[518]=0.f; feat[519]=0.f;
  }
  __syncthreads();
  {
    float sc = qs[si], inv = 1.f/sc;
    const float* row = w1 + ((size_t)si*256 + tid)*519;
    float acc=0.f;
    for (int k=0;k<519;++k){
      float q = rintf(row[k]*inv);
      q = fminf(fmaxf(q,-128.f),127.f);
      acc += feat[k]*(q*sc);
    }
    h1[tid]=fmaxf(acc,0.f);
  }
  __syncthreads();
  {
    float sc = qs[3+si], inv = 1.f/sc;
    const float* row = w2 + ((size_t)si*256 + tid)*256;
    float acc=0.f;
    for (int k=0;k<256;++k){
      float q = rintf(row[k]*inv);
      q = fminf(fmaxf(q,-128.f),127.f);
      acc += h1[k]*(q*sc);
    }
    h2[tid]=fmaxf(acc,0.f);
  }
  __syncthreads();
  int nout = (si==1)?125:165;
  const float* w3 = (si==0)?w30:((si==1)?w31:w32);
  if (tid<nout){
    float sc = qs[6+si], inv = 1.f/sc;
    const float* row = w3 + (size_t)tid*256;
    float acc=0.f;
    for (int k=0;k<256;++k){
      float q = rintf(row[k]*inv);
      q = fminf(fmaxf(q,-128.f),127.f);
      acc += h2[k]*(q*sc);
    }
    o[tid]=acc;
  }
  __syncthreads();
  if (tid==0){
    int b = (si==1)?60:80;
    const float* sw = (si==0)?sw0:((si==1)?sw1:sw2);
    const float* ew = (si==0)?ew0:((si==1)?ew1:ew2);
    float m=-1e30f; for (int i=0;i<b;++i) m=fmaxf(m,o[i]);
    float se=0.f, wsum=0.f;
    for (int i=0;i<b;++i){ float t=expf(o[i]-m); se+=t; wsum+=t*sw[i]; }
    float so = wsum/se;
    m=-1e30f; for (int i=0;i<b;++i) m=fmaxf(m,o[b+i]);
    se=0.f; wsum=0.f;
    for (int i=0;i<b;++i){ float t=expf(o[b+i]-m); se+=t; wsum+=t*ew[i]; }
    float eo = wsum/se;
    out[2*a]   = fminf(fmaxf(s+so,0.f),al);
    out[2*a+1] = fminf(fmaxf(e+eo,0.f),al);
    out[140+a] = o[2*b];
    for (int c2=0;c2<4;++c2) out[210+4*a+c2] = o[2*b+1+c2];
  }
}

extern "C" void kernel_launch(void* const* d_in, const int* in_sizes, int n_in,
                              void* d_out, int out_size, void* d_ws, size_t ws_size,
                              hipStream_t stream){
  const float* emb   = (const float*)d_in[0];
  const float* tpin  = (const float*)d_in[1];
  const float* npred = (const float*)d_in[2];
  const float* alen  = (const float*)d_in[3];
  const float* anch  = (const float*)d_in[4];
  const float* wih   = (const float*)d_in[5];
  const float* whh   = (const float*)d_in[6];
  const float* bih   = (const float*)d_in[7];
  const float* bhh   = (const float*)d_in[8];
  const float* w1    = (const float*)d_in[9];
  const float* w2    = (const float*)d_in[10];
  const float* w30   = (const float*)d_in[11];
  const float* w31   = (const float*)d_in[12];
  const float* w32   = (const float*)d_in[13];
  const float* sw0   = (const float*)d_in[14];
  const float* ew0   = (const float*)d_in[15];
  const float* sw1   = (const float*)d_in[16];
  const float* ew1   = (const float*)d_in[17];
  const float* sw2   = (const float*)d_in[18];
  const float* ew2   = (const float*)d_in[19];

  char* ws = (char*)d_ws;
  size_t off = 0;
  auto take = [&](size_t bytes)->char*{
    char* p = ws + off;
    off = (off + bytes + 255) & ~(size_t)255;
    return p;
  };
  float* tpos   = (float*)take((size_t)NN*4);
  float* abn    = (float*)take((size_t)NN*4);
  int*   order_ = (int*)  take((size_t)NA*MAXT*4);
  int*   cnteff = (int*)  take((size_t)NA*2*4);
  float* qs     = (float*)take(16*4);
  uint4* whhB   = (uint4*)take((size_t)6*8*64*48*16);
  float* E      = (float*)take((size_t)6*NNP*1024*4);
  float* hout   = (float*)take((size_t)NA*2*DD*4);
  (void)ws_size; (void)in_sizes; (void)n_in; (void)out_size;

  prep_kernel<<<dim3((NN+255)/256), dim3(256), 0, stream>>>(tpin, npred, alen, tpos, abn);
  order_kernel<<<dim3(NA), dim3(64), 0, stream>>>(tpos, anch, order_, cnteff);
  pack_whhB<<<dim3((6*8*64*48+255)/256), dim3(256), 0, stream>>>(whh, whhB);
  e_gemm<<<dim3(16,12,6), dim3(256), 0, stream>>>(emb, wih, bih, bhh, E);
  fill_bias<<<dim3((6*8*16*6+255)/256), dim3(256), 0, stream>>>(bih, bhh, E);
  absmax_kernel<<<dim3(9), dim3(256), 0, stream>>>(w1, w2, w30, w31, w32, qs);
  gru_kernel<<<dim3(NA*2), dim3(512), 0, stream>>>(E, whhB, bhh, order_, cnteff, hout);
  mlp_kernel<<<dim3(NA), dim3(256), 0, stream>>>(hout, abn, anch, alen, w1, w2, w30, w31, w32,
                                                 sw0, ew0, sw1, ew1, sw2, ew2, qs, (float*)d_out);
}

// Round 6
// 704.988 us; speedup vs baseline: 1.0344x; 1.0344x over previous
//
#include <hip/hip_runtime.h>
#include <math.h>

#define NN 1024
#define NNP 1025
#define DD 256
#define CC 5
#define G3 768
#define MAXT 512
#define NA 70
#define PW3 176

typedef _Float16 v8h __attribute__((ext_vector_type(8)));
typedef float v4f __attribute__((ext_vector_type(4)));

__device__ __forceinline__ int scale_of(int a){ return (a<15)?0:((a<55)?1:2); }
__device__ __forceinline__ int off_of(int s){ return (s==0)?0:((s==1)?15:55); }

__device__ __forceinline__ float sigf(float x){ return __fdividef(1.f, 1.f + __expf(-x)); }
__device__ __forceinline__ float tanhf_fast(float x){ return 1.f - __fdividef(2.f, __expf(2.f*x) + 1.f); }

// K0: abn = softmax(node_pred)[:,0]
__global__ void abn_kernel(const float* __restrict__ node_pred, float* __restrict__ abn){
  int i = blockIdx.x*blockDim.x + threadIdx.x;
  if (i >= NN) return;
  float pv[CC]; float m = -1e30f;
  for (int c=0;c<CC;++c){ pv[c]=node_pred[i*CC+c]; m=fmaxf(m,pv[c]); }
  float s=0.f;
  for (int c=0;c<CC;++c) s += expf(pv[c]-m);
  abn[i] = expf(pv[0]-m)/s;
}

// K1: per-anchor stable gather of masked node indices + counts (ballot prefix)
__global__ void order_kernel(const float* __restrict__ tp_in, const float* __restrict__ audio_len,
                             const float* __restrict__ anchors,
                             int* __restrict__ order, int* __restrict__ cnteff){
  int a = blockIdx.x; int lane = threadIdx.x; // 64 threads = 1 wave
  float al = audio_len[0];
  float s = anchors[2*a], e = anchors[2*a+1];
  int* ord = order + a*MAXT;
  int cnt = 0;
  for (int base=0; base<NN; base+=64){
    float tp = tp_in[base+lane]*al;
    bool msk = (tp>=s)&&(tp<=e);
    unsigned long long bal = __ballot(msk);
    int off = (int)__popcll(bal & ((1ull<<lane)-1ull));
    if (msk && (cnt+off)<MAXT) ord[cnt+off] = base+lane;
    cnt += (int)__popcll(bal);
  }
  if (lane==0){ int c = cnt<MAXT?cnt:MAXT; cnteff[2*a]=c; cnteff[2*a+1]=(c>0)?c:1; }
}

// K2: pack whh into MFMA B-fragments grouped per-wave as 6 col-tiles:
// nt0,1 = r cols [w*32+0..15],[+16..31]; nt2,3 = z; nt4,5 = n.
__global__ void pack_whhB(const float* __restrict__ whh, uint4* __restrict__ dst){
  int i = blockIdx.x*256 + threadIdx.x;
  if (i >= 6*8*64*48) return;
  int q    = i & 7;
  int nt   = (i>>3) % 6;
  int lane = (i/48) & 63;
  int wv   = (i/3072) & 7;
  int sd   = i/24576;
  int gt = nt>>1, half = nt&1;
  int j = gt*256 + wv*32 + half*16 + (lane&15);
  int kbase = 32*q + 8*(lane>>4);
  const float* src = whh + ((size_t)sd*G3 + j)*DD + kbase;
  unsigned int u[4];
  #pragma unroll
  for (int rp=0;rp<4;++rp){
    _Float16 a = (_Float16)src[2*rp];
    _Float16 b = (_Float16)src[2*rp+1];
    unsigned short ua = __builtin_bit_cast(unsigned short, a);
    unsigned short ub = __builtin_bit_cast(unsigned short, b);
    u[rp] = (unsigned int)ua | ((unsigned int)ub<<16);
  }
  uint4 v; v.x=u[0]; v.y=u[1]; v.z=u[2]; v.w=u[3];
  dst[i] = v;
}

// K3: E16[sd][node][w][cl][slot(8)] fp16 = emb.wih^T + bih (+bhh for r,z slots)
// slots: 0:r0 1:z0 2:n0 3:r16 4:z16 5:n16 6,7:pad
__global__ __launch_bounds__(256) void e_gemm(const float* __restrict__ emb, const float* __restrict__ wih,
                       const float* __restrict__ bih, const float* __restrict__ bhh,
                       _Float16* __restrict__ E){
  int sd = blockIdx.z;
  int row0 = blockIdx.x*64, col0 = blockIdx.y*64;
  const float* W = wih + (size_t)sd*G3*DD;
  __shared__ float As[64][65];
  __shared__ float Bs[64][65];
  int tid = threadIdx.x;
  int tr = tid>>4, tc = tid&15;
  float acc[4][4] = {};
  for (int kb=0; kb<4; ++kb){
    for (int i=0;i<4;++i){
      int e4 = i*256 + tid;
      int rr = e4>>4, qq = e4&15;
      float4 av = reinterpret_cast<const float4*>(emb)[ (size_t)(row0+rr)*64 + kb*16 + qq ];
      As[rr][qq*4+0]=av.x; As[rr][qq*4+1]=av.y; As[rr][qq*4+2]=av.z; As[rr][qq*4+3]=av.w;
      float4 bv = reinterpret_cast<const float4*>(W)[ (size_t)(col0+rr)*64 + kb*16 + qq ];
      Bs[rr][qq*4+0]=bv.x; Bs[rr][qq*4+1]=bv.y; Bs[rr][qq*4+2]=bv.z; Bs[rr][qq*4+3]=bv.w;
    }
    __syncthreads();
    for (int k=0;k<64;++k){
      float a0[4], b0[4];
      #pragma unroll
      for (int i=0;i<4;++i) a0[i]=As[tr*4+i][k];
      #pragma unroll
      for (int j=0;j<4;++j) b0[j]=Bs[tc*4+j][k];
      #pragma unroll
      for (int i=0;i<4;++i)
        #pragma unroll
        for (int j=0;j<4;++j)
          acc[i][j] += a0[i]*b0[j];
    }
    __syncthreads();
  }
  for (int i=0;i<4;++i){
    int row = row0 + tr*4 + i;
    for (int j=0;j<4;++j){
      int col = col0 + tc*4 + j;
      int gt = col>>8; int c = col&255;
      int wv = c>>5; int mm = c&31; int half = mm>>4; int cl = mm&15;
      int slot = half*3 + gt;
      float val = acc[i][j] + bih[sd*G3+col] + ((gt<2)? bhh[sd*G3+col] : 0.f);
      E[(((size_t)sd*NNP + row)*8 + wv)*128 + cl*8 + slot] = (_Float16)val;
    }
  }
}

// K3b: fake node row NN = pure bias (used for masked steps / cnt==0)
__global__ void fill_bias(const float* __restrict__ bih, const float* __restrict__ bhh,
                          _Float16* __restrict__ E){
  int i = blockIdx.x*256 + threadIdx.x;   // 6*8*16*6 = 4608
  if (i >= 6*8*16*6) return;
  int slot = i % 6; int cl = (i/6)&15; int wv = (i/96)&7; int sd = i/768;
  int half = slot/3, gt = slot%3;
  int j = gt*256 + wv*32 + half*16 + cl;
  float v = bih[sd*G3+j] + ((gt<2)? bhh[sd*G3+j] : 0.f);
  E[(((size_t)sd*NNP + NN)*8 + wv)*128 + cl*8 + slot] = (_Float16)v;
}

// K4: per-matrix absmax -> quant scale (9 matrices)
__global__ void absmax_kernel(const float* __restrict__ w1, const float* __restrict__ w2,
                              const float* __restrict__ w30, const float* __restrict__ w31,
                              const float* __restrict__ w32, float* __restrict__ qs){
  int m = blockIdx.x, tid = threadIdx.x;
  const float* p; int n;
  if (m<3){ p = w1 + (size_t)m*256*519; n = 256*519; }
  else if (m<6){ p = w2 + (size_t)(m-3)*256*256; n = 256*256; }
  else { p = (m==6)?w30:((m==7)?w31:w32); n = ((m==7)?125:165)*256; }
  float mx = 0.f;
  for (int i=tid;i<n;i+=256) mx = fmaxf(mx, fabsf(p[i]));
  __shared__ float red[256];
  red[tid]=mx; __syncthreads();
  for (int sft=128; sft>0; sft>>=1){ if (tid<sft) red[tid]=fmaxf(red[tid],red[tid+sft]); __syncthreads(); }
  if (tid==0) qs[m] = fmaxf(red[0]/127.f, 1e-8f);
}

// K4b: pre-quantize + transpose MLP weights (k-major, coalesced for mlp)
__global__ void tq_all(const float* __restrict__ w1, const float* __restrict__ w2,
                       const float* __restrict__ w30, const float* __restrict__ w31,
                       const float* __restrict__ w32, const float* __restrict__ qs,
                       float* __restrict__ w1T, float* __restrict__ w2T, float* __restrict__ w3T){
  int i = blockIdx.x*256 + threadIdx.x;
  const int N1 = 3*520*256, N2 = 3*256*256, N3 = 3*256*PW3;
  if (i < N1){
    int j = i&255; int k=(i>>8)%520; int si=i/(520*256);
    float v=0.f;
    if (k<519){ float sc=qs[si]; float q=rintf(w1[((size_t)si*256+j)*519+k]/sc);
                q=fminf(fmaxf(q,-128.f),127.f); v=q*sc; }
    w1T[((size_t)si*520+k)*256+j]=v;
  } else if (i < N1+N2){
    int r=i-N1; int j=r&255; int k=(r>>8)&255; int si=r>>16;
    float sc=qs[3+si]; float q=rintf(w2[((size_t)si*256+j)*256+k]/sc);
    q=fminf(fmaxf(q,-128.f),127.f);
    w2T[((size_t)si*256+k)*256+j]=q*sc;
  } else if (i < N1+N2+N3){
    int r=i-N1-N2; int j=r%PW3; int k=(r/PW3)&255; int si=r/(256*PW3);
    int nout=(si==1)?125:165;
    const float* w3 = (si==0)?w30:((si==1)?w31:w32);
    float v=0.f;
    if (j<nout){ float sc=qs[6+si]; float q=rintf(w3[(size_t)j*256+k]/sc);
                 q=fminf(fmaxf(q,-128.f),127.f); v=q*sc; }
    w3T[((size_t)si*256+k)*PW3+j]=v;
  }
}

// K5: sequential GRU. One block per (anchor, direction); 8 waves x 96 gates.
// Lane-local nonlinearity; prefetch of the NEXT E row issued at the TOP of the
// step so the 48-MFMA phase covers its latency before the barrier's vmcnt drain.
__global__ __launch_bounds__(512, 2) void gru_kernel(
                           const _Float16* __restrict__ E, const uint4* __restrict__ whhB,
                           const float* __restrict__ bhh,
                           const int* __restrict__ order, const int* __restrict__ cnteff,
                           float* __restrict__ hout){
  int a = blockIdx.x>>1, d = blockIdx.x&1;
  int si = scale_of(a);
  int sd = si*2+d;
  int tid = threadIdx.x;
  int w = tid>>6, lane = tid&63;
  int l15 = lane&15, g16 = lane>>4;

  __shared__ int ord_s[MAXT];
  __shared__ alignas(16) _Float16 h16[2][DD];

  ord_s[tid] = order[a*MAXT + tid];
  if (tid < DD) h16[0][tid] = (_Float16)0.f;

  int cnt = cnteff[2*a], eff = cnteff[2*a+1];

  int c0 = w*32 + l15, c1 = c0 + 16;
  float bn0 = bhh[sd*G3 + 2*DD + c0];
  float bn1 = bhh[sd*G3 + 2*DD + c1];

  // B fragments: 48 x uint4 = 192 dwords resident
  v8h bf[6][8];
  {
    const uint4* wp = whhB + (((size_t)sd*8 + w)*64 + lane)*48;
    #pragma unroll
    for (int nt=0;nt<6;++nt)
      #pragma unroll
      for (int q=0;q<8;++q)
        bf[nt][q] = __builtin_bit_cast(v8h, wp[nt*8+q]);
  }

  const uint4* Eb = reinterpret_cast<const uint4*>(E) + (size_t)sd*NNP*128;
  int li = w*16 + l15;

  float h0 = 0.f, h1 = 0.f;
  uint4 gEven, gOdd;
  {
    int idx0 = d ? (eff-1) : 0;
    int n0 = (idx0 < cnt) ? ord_s[idx0] : NN;
    gEven = Eb[(size_t)n0*128 + li];
  }
  __syncthreads();   // covers ord_s/h16 init; drains prologue load

  for (int t=0;t<eff;++t){
    int p = t & 1;
    // hoisted prefetch issue for step t+1 (covered by this step's MFMA phase)
    if (t+1 < eff){
      int idx1 = d ? (eff-2-t) : (t+1);
      int n1 = (idx1 < cnt) ? ord_s[idx1] : NN;
      if (p==0) gOdd  = Eb[(size_t)n1*128 + li];
      else      gEven = Eb[(size_t)n1*128 + li];
    }
    v4f acc0={0.f,0.f,0.f,0.f}, acc1={0.f,0.f,0.f,0.f};
    v4f acc2={0.f,0.f,0.f,0.f}, acc3={0.f,0.f,0.f,0.f};
    v4f acc4={bn0,bn0,bn0,bn0}, acc5={bn1,bn1,bn1,bn1};
    #pragma unroll
    for (int q=0;q<8;++q){
      v8h af = *reinterpret_cast<const v8h*>(&h16[p][32*q + 8*g16]);
      acc0 = __builtin_amdgcn_mfma_f32_16x16x32_f16(af, bf[0][q], acc0, 0,0,0);
      acc1 = __builtin_amdgcn_mfma_f32_16x16x32_f16(af, bf[1][q], acc1, 0,0,0);
      acc2 = __builtin_amdgcn_mfma_f32_16x16x32_f16(af, bf[2][q], acc2, 0,0,0);
      acc3 = __builtin_amdgcn_mfma_f32_16x16x32_f16(af, bf[3][q], acc3, 0,0,0);
      acc4 = __builtin_amdgcn_mfma_f32_16x16x32_f16(af, bf[4][q], acc4, 0,0,0);
      acc5 = __builtin_amdgcn_mfma_f32_16x16x32_f16(af, bf[5][q], acc5, 0,0,0);
    }
    v8h ev = __builtin_bit_cast(v8h, (p==0) ? gEven : gOdd);
    // lane-local GRU cell for columns c0, c1
    float r0 = sigf((float)ev[0] + acc0[0]);
    float z0 = sigf((float)ev[1] + acc2[0]);
    float n0v = tanhf_fast((float)ev[2] + r0*acc4[0]);
    h0 = z0*(h0 - n0v) + n0v;
    float r1 = sigf((float)ev[3] + acc1[0]);
    float z1 = sigf((float)ev[4] + acc3[0]);
    float n1v = tanhf_fast((float)ev[5] + r1*acc5[0]);
    h1 = z1*(h1 - n1v) + n1v;
    if (g16 == 0)      h16[p^1][c0] = (_Float16)h0;
    else if (g16 == 1) h16[p^1][c1] = (_Float16)h1;
    __syncthreads();
  }
  if (g16 == 0)      hout[(size_t)(2*a+d)*DD + c0] = h0;
  else if (g16 == 1) hout[(size_t)(2*a+d)*DD + c1] = h1;
}

// K6: per-anchor MLP (pre-quantized transposed weights, coalesced k-major) + head
__global__ __launch_bounds__(256) void mlp_kernel(const float* __restrict__ hout, const float* __restrict__ abn,
                           const float* __restrict__ anchors, const float* __restrict__ audio_len,
                           const float* __restrict__ w1T, const float* __restrict__ w2T,
                           const float* __restrict__ w3T,
                           const float* __restrict__ sw0, const float* __restrict__ ew0,
                           const float* __restrict__ sw1, const float* __restrict__ ew1,
                           const float* __restrict__ sw2, const float* __restrict__ ew2,
                           float* __restrict__ out){
  int a = blockIdx.x, tid = threadIdx.x;
  int si = scale_of(a);
  int il = a - off_of(si);
  float s = anchors[2*a], e = anchors[2*a+1];
  float al = audio_len[0];
  __shared__ float feat[520];
  __shared__ float h1[256], h2[256], o[PW3];
  feat[tid]    = hout[(size_t)(2*a+0)*DD + tid];
  feat[DD+tid] = hout[(size_t)(2*a+1)*DD + tid];
  if (tid==0){
    feat[512]=abn[il];
    feat[513]=(s+e)*0.5f/al;
    feat[514]=(e-s)/al;
    feat[515]=0.f; feat[516]=0.f; feat[517]=0.f; feat[518]=0.f; feat[519]=0.f;
  }
  __syncthreads();
  {
    const float* p1 = w1T + (size_t)si*520*256 + tid;
    float acc=0.f;
    #pragma unroll 4
    for (int k=0;k<519;++k) acc += feat[k]*p1[(size_t)k*256];
    h1[tid]=fmaxf(acc,0.f);
  }
  __syncthreads();
  {
    const float* p2 = w2T + (size_t)si*256*256 + tid;
    float acc=0.f;
    #pragma unroll 4
    for (int k=0;k<256;++k) acc += h1[k]*p2[(size_t)k*256];
    h2[tid]=fmaxf(acc,0.f);
  }
  __syncthreads();
  if (tid<PW3){
    const float* p3 = w3T + (size_t)si*256*PW3 + tid;
    float acc=0.f;
    #pragma unroll 4
    for (int k=0;k<256;++k) acc += h2[k]*p3[(size_t)k*PW3];
    o[tid]=acc;
  }
  __syncthreads();
  if (tid==0){
    int b = (si==1)?60:80;
    const float* sw = (si==0)?sw0:((si==1)?sw1:sw2);
    const float* ew = (si==0)?ew0:((si==1)?ew1:ew2);
    float m=-1e30f; for (int i=0;i<b;++i) m=fmaxf(m,o[i]);
    float se=0.f, wsum=0.f;
    for (int i=0;i<b;++i){ float t=expf(o[i]-m); se+=t; wsum+=t*sw[i]; }
    float so = wsum/se;
    m=-1e30f; for (int i=0;i<b;++i) m=fmaxf(m,o[b+i]);
    se=0.f; wsum=0.f;
    for (int i=0;i<b;++i){ float t=expf(o[b+i]-m); se+=t; wsum+=t*ew[i]; }
    float eo = wsum/se;
    out[2*a]   = fminf(fmaxf(s+so,0.f),al);
    out[2*a+1] = fminf(fmaxf(e+eo,0.f),al);
    out[140+a] = o[2*b];
    for (int c2=0;c2<4;++c2) out[210+4*a+c2] = o[2*b+1+c2];
  }
}

extern "C" void kernel_launch(void* const* d_in, const int* in_sizes, int n_in,
                              void* d_out, int out_size, void* d_ws, size_t ws_size,
                              hipStream_t stream){
  const float* emb   = (const float*)d_in[0];
  const float* tpin  = (const float*)d_in[1];
  const float* npred = (const float*)d_in[2];
  const float* alen  = (const float*)d_in[3];
  const float* anch  = (const float*)d_in[4];
  const float* wih   = (const float*)d_in[5];
  const float* whh   = (const float*)d_in[6];
  const float* bih   = (const float*)d_in[7];
  const float* bhh   = (const float*)d_in[8];
  const float* w1    = (const float*)d_in[9];
  const float* w2    = (const float*)d_in[10];
  const float* w30   = (const float*)d_in[11];
  const float* w31   = (const float*)d_in[12];
  const float* w32   = (const float*)d_in[13];
  const float* sw0   = (const float*)d_in[14];
  const float* ew0   = (const float*)d_in[15];
  const float* sw1   = (const float*)d_in[16];
  const float* ew1   = (const float*)d_in[17];
  const float* sw2   = (const float*)d_in[18];
  const float* ew2   = (const float*)d_in[19];

  char* ws = (char*)d_ws;
  size_t off = 0;
  auto take = [&](size_t bytes)->char*{
    char* p = ws + off;
    off = (off + bytes + 255) & ~(size_t)255;
    return p;
  };
  float* abn    = (float*)take((size_t)NN*4);
  int*   order_ = (int*)  take((size_t)NA*MAXT*4);
  int*   cnteff = (int*)  take((size_t)NA*2*4);
  float* qs     = (float*)take(16*4);
  uint4* whhB   = (uint4*)take((size_t)6*8*64*48*16);
  _Float16* E   = (_Float16*)take((size_t)6*NNP*1024*2);
  float* hout   = (float*)take((size_t)NA*2*DD*4);
  float* w1T    = (float*)take((size_t)3*520*256*4);
  float* w2T    = (float*)take((size_t)3*256*256*4);
  float* w3T    = (float*)take((size_t)3*256*PW3*4);
  (void)ws_size; (void)in_sizes; (void)n_in; (void)out_size;

  abn_kernel<<<dim3((NN+255)/256), dim3(256), 0, stream>>>(npred, abn);
  order_kernel<<<dim3(NA), dim3(64), 0, stream>>>(tpin, alen, anch, order_, cnteff);
  pack_whhB<<<dim3((6*8*64*48+255)/256), dim3(256), 0, stream>>>(whh, whhB);
  e_gemm<<<dim3(16,12,6), dim3(256), 0, stream>>>(emb, wih, bih, bhh, E);
  fill_bias<<<dim3((6*8*16*6+255)/256), dim3(256), 0, stream>>>(bih, bhh, E);
  absmax_kernel<<<dim3(9), dim3(256), 0, stream>>>(w1, w2, w30, w31, w32, qs);
  {
    const int NT = 3*520*256 + 3*256*256 + 3*256*PW3;
    tq_all<<<dim3((NT+255)/256), dim3(256), 0, stream>>>(w1, w2, w30, w31, w32, qs, w1T, w2T, w3T);
  }
  gru_kernel<<<dim3(NA*2), dim3(512), 0, stream>>>(E, whhB, bhh, order_, cnteff, hout);
  mlp_kernel<<<dim3(NA), dim3(256), 0, stream>>>(hout, abn, anch, alen, w1T, w2T, w3T,
                                                 sw0, ew0, sw1, ew1, sw2, ew2, (float*)d_out);
}

// Round 7
// 599.760 us; speedup vs baseline: 1.2159x; 1.1754x over previous
//
#include <hip/hip_runtime.h>
#include <math.h>

#define NN 1024
#define NNP 1025
#define DD 256
#define CC 5
#define G3 768
#define MAXT 512
#define NA 70
#define PW3 176

typedef _Float16 v8h __attribute__((ext_vector_type(8)));
typedef float v4f __attribute__((ext_vector_type(4)));
typedef int v4i __attribute__((ext_vector_type(4)));

__device__ __forceinline__ int scale_of(int a){ return (a<15)?0:((a<55)?1:2); }
__device__ __forceinline__ int off_of(int s){ return (s==0)?0:((s==1)?15:55); }

__device__ __forceinline__ float sigf(float x){ return __fdividef(1.f, 1.f + __expf(-x)); }
__device__ __forceinline__ float tanhf_fast(float x){ return 1.f - __fdividef(2.f, __expf(2.f*x) + 1.f); }

// ---------------- PREP mega-kernel ----------------
// blocks 0..3    : abn = softmax(node_pred)[:,0]
// blocks 4..73   : per-anchor stable gather (order/cnteff)
// blocks 74..82  : absmax -> qs (9 MLP matrices)
// blocks 83..100 : whh per-column absmax -> cm[6*768]
// blocks 101..118: fill fake bias row NN of E (fp16)
__global__ __launch_bounds__(256) void prep_kernel(
    const float* __restrict__ node_pred, const float* __restrict__ tp_in,
    const float* __restrict__ audio_len, const float* __restrict__ anchors,
    const float* __restrict__ whh,
    const float* __restrict__ bih, const float* __restrict__ bhh,
    const float* __restrict__ w1, const float* __restrict__ w2,
    const float* __restrict__ w30, const float* __restrict__ w31, const float* __restrict__ w32,
    float* __restrict__ abn, int* __restrict__ order, int* __restrict__ cnteff,
    float* __restrict__ qs, float* __restrict__ cm, _Float16* __restrict__ E){
  int b = blockIdx.x, tid = threadIdx.x;
  if (b < 4){
    int i = b*256 + tid;
    float pv[CC]; float m = -1e30f;
    for (int c=0;c<CC;++c){ pv[c]=node_pred[i*CC+c]; m=fmaxf(m,pv[c]); }
    float s=0.f;
    for (int c=0;c<CC;++c) s += expf(pv[c]-m);
    abn[i] = expf(pv[0]-m)/s;
  } else if (b < 74){
    if (tid >= 64) return;
    int a = b-4; int lane = tid;
    float al = audio_len[0];
    float s = anchors[2*a], e = anchors[2*a+1];
    int* ord = order + a*MAXT;
    int cnt = 0;
    for (int base=0; base<NN; base+=64){
      float tp = tp_in[base+lane]*al;
      bool msk = (tp>=s)&&(tp<=e);
      unsigned long long bal = __ballot(msk);
      int off = (int)__popcll(bal & ((1ull<<lane)-1ull));
      if (msk && (cnt+off)<MAXT) ord[cnt+off] = base+lane;
      cnt += (int)__popcll(bal);
    }
    if (lane==0){ int c = cnt<MAXT?cnt:MAXT; cnteff[2*a]=c; cnteff[2*a+1]=(c>0)?c:1; }
  } else if (b < 83){
    int m = b-74;
    const float* p; int n;
    if (m<3){ p = w1 + (size_t)m*256*519; n = 256*519; }
    else if (m<6){ p = w2 + (size_t)(m-3)*256*256; n = 256*256; }
    else { p = (m==6)?w30:((m==7)?w31:w32); n = ((m==7)?125:165)*256; }
    float mx = 0.f;
    for (int i=tid;i<n;i+=256) mx = fmaxf(mx, fabsf(p[i]));
    __shared__ float red[256];
    red[tid]=mx; __syncthreads();
    for (int sft=128; sft>0; sft>>=1){ if (tid<sft) red[tid]=fmaxf(red[tid],red[tid+sft]); __syncthreads(); }
    if (tid==0) qs[m] = fmaxf(red[0]/127.f, 1e-8f);
  } else if (b < 101){
    int idx = (b-83)*256 + tid;           // sd*768 + j
    if (idx >= 6*G3) return;
    const float4* src = reinterpret_cast<const float4*>(whh + (size_t)idx*DD);
    float mx = 0.f;
    #pragma unroll 8
    for (int i=0;i<64;++i){
      float4 v = src[i];
      mx = fmaxf(mx, fmaxf(fmaxf(fabsf(v.x),fabsf(v.y)), fmaxf(fabsf(v.z),fabsf(v.w))));
    }
    cm[idx] = fmaxf(mx, 1e-12f);
  } else {
    int i = (b-101)*256 + tid;            // 6*8*16*6 = 4608
    if (i >= 6*8*16*6) return;
    int slot = i % 6; int cl = (i/6)&15; int wv = (i/96)&7; int sd = i/768;
    int half = slot/3, gt = slot%3;
    int j = gt*256 + wv*32 + half*16 + cl;
    float v = bih[sd*G3+j] + ((gt<2)? bhh[sd*G3+j] : 0.f);
    E[(((size_t)sd*NNP + NN)*8 + wv)*128 + cl*8 + slot] = (_Float16)v;
  }
}

// ---------------- QUANT kernel: pack whh int8 fragments + pre-quant MLP weights ----------------
// blocks 0..287: whhB8 fragments, one uint4 (16 int8) per thread
//   i = (((sd*8+w)*64+lane)*6 + nt)*4 + q ; col j = (nt>>1)*256 + w*32 + (nt&1)*16 + (lane&15)
//   k = 64q + 16*(lane>>4) + e
// blocks 288.. : tq (w1T/w2T/w3T)
__global__ __launch_bounds__(256) void quant_kernel(
    const float* __restrict__ whh, const float* __restrict__ cm,
    const float* __restrict__ w1, const float* __restrict__ w2,
    const float* __restrict__ w30, const float* __restrict__ w31, const float* __restrict__ w32,
    const float* __restrict__ qs,
    uint4* __restrict__ whhB8, float* __restrict__ w1T, float* __restrict__ w2T, float* __restrict__ w3T){
  int b = blockIdx.x, tid = threadIdx.x;
  if (b < 288){
    int i = b*256 + tid;                  // < 6*8*64*24 = 73728
    int q    = i & 3;
    int nt   = (i>>2) % 6;
    int lane = (i/24) & 63;
    int wv   = (i/1536) & 7;
    int sd   = i/12288;
    int gt = nt>>1, half = nt&1;
    int j = gt*256 + wv*32 + half*16 + (lane&15);
    int kbase = 64*q + 16*(lane>>4);
    float cmax = cm[sd*G3 + j];
    float inv = 127.f/cmax;
    const float* src = whh + ((size_t)sd*G3 + j)*DD + kbase;
    unsigned int dw[4];
    #pragma unroll
    for (int d2=0; d2<4; ++d2){
      unsigned int acc = 0;
      #pragma unroll
      for (int e2=0; e2<4; ++e2){
        float qv = rintf(src[4*d2+e2]*inv);
        qv = fminf(fmaxf(qv,-127.f),127.f);
        int iq = (int)qv;
        acc |= ((unsigned int)(iq & 255)) << (8*e2);
      }
      dw[d2] = acc;
    }
    uint4 v; v.x=dw[0]; v.y=dw[1]; v.z=dw[2]; v.w=dw[3];
    whhB8[i] = v;
  } else {
    int i = (b-288)*256 + tid;
    const int N1 = 3*520*256, N2 = 3*256*256, N3 = 3*256*PW3;
    if (i < N1){
      int j = i&255; int k=(i>>8)%520; int si=i/(520*256);
      float v=0.f;
      if (k<519){ float sc=qs[si]; float q=rintf(w1[((size_t)si*256+j)*519+k]/sc);
                  q=fminf(fmaxf(q,-128.f),127.f); v=q*sc; }
      w1T[((size_t)si*520+k)*256+j]=v;
    } else if (i < N1+N2){
      int r=i-N1; int j=r&255; int k=(r>>8)&255; int si=r>>16;
      float sc=qs[3+si]; float q=rintf(w2[((size_t)si*256+j)*256+k]/sc);
      q=fminf(fmaxf(q,-128.f),127.f);
      w2T[((size_t)si*256+k)*256+j]=q*sc;
    } else if (i < N1+N2+N3){
      int r=i-N1-N2; int j=r%PW3; int k=(r/PW3)&255; int si=r/(256*PW3);
      int nout=(si==1)?125:165;
      const float* w3 = (si==0)?w30:((si==1)?w31:w32);
      float v=0.f;
      if (j<nout){ float sc=qs[6+si]; float q=rintf(w3[(size_t)j*256+k]/sc);
                   q=fminf(fmaxf(q,-128.f),127.f); v=q*sc; }
      w3T[((size_t)si*256+k)*PW3+j]=v;
    }
  }
}

// ---------------- E-GEMM (fp16 out, permuted slots, biases folded) ----------------
__global__ __launch_bounds__(256) void e_gemm(const float* __restrict__ emb, const float* __restrict__ wih,
                       const float* __restrict__ bih, const float* __restrict__ bhh,
                       _Float16* __restrict__ E){
  int sd = blockIdx.z;
  int row0 = blockIdx.x*64, col0 = blockIdx.y*64;
  const float* W = wih + (size_t)sd*G3*DD;
  __shared__ float As[64][65];
  __shared__ float Bs[64][65];
  int tid = threadIdx.x;
  int tr = tid>>4, tc = tid&15;
  float acc[4][4] = {};
  for (int kb=0; kb<4; ++kb){
    for (int i=0;i<4;++i){
      int e4 = i*256 + tid;
      int rr = e4>>4, qq = e4&15;
      float4 av = reinterpret_cast<const float4*>(emb)[ (size_t)(row0+rr)*64 + kb*16 + qq ];
      As[rr][qq*4+0]=av.x; As[rr][qq*4+1]=av.y; As[rr][qq*4+2]=av.z; As[rr][qq*4+3]=av.w;
      float4 bv = reinterpret_cast<const float4*>(W)[ (size_t)(col0+rr)*64 + kb*16 + qq ];
      Bs[rr][qq*4+0]=bv.x; Bs[rr][qq*4+1]=bv.y; Bs[rr][qq*4+2]=bv.z; Bs[rr][qq*4+3]=bv.w;
    }
    __syncthreads();
    for (int k=0;k<64;++k){
      float a0[4], b0[4];
      #pragma unroll
      for (int i=0;i<4;++i) a0[i]=As[tr*4+i][k];
      #pragma unroll
      for (int j=0;j<4;++j) b0[j]=Bs[tc*4+j][k];
      #pragma unroll
      for (int i=0;i<4;++i)
        #pragma unroll
        for (int j=0;j<4;++j)
          acc[i][j] += a0[i]*b0[j];
    }
    __syncthreads();
  }
  for (int i=0;i<4;++i){
    int row = row0 + tr*4 + i;
    for (int j=0;j<4;++j){
      int col = col0 + tc*4 + j;
      int gt = col>>8; int c = col&255;
      int wv = c>>5; int mm = c&31; int half = mm>>4; int cl = mm&15;
      int slot = half*3 + gt;
      float val = acc[i][j] + bih[sd*G3+col] + ((gt<2)? bhh[sd*G3+col] : 0.f);
      E[(((size_t)sd*NNP + row)*8 + wv)*128 + cl*8 + slot] = (_Float16)val;
    }
  }
}

// ---------------- GRU: int8 MFMA (16x16x64), h carried fp32, broadcast int8 via LDS ----------------
__global__ __launch_bounds__(512, 2) void gru_kernel(
                           const _Float16* __restrict__ E, const v4i* __restrict__ whhB8,
                           const float* __restrict__ bhh, const float* __restrict__ cm,
                           const int* __restrict__ order, const int* __restrict__ cnteff,
                           float* __restrict__ hout){
  int a = blockIdx.x>>1, d = blockIdx.x&1;
  int si = scale_of(a);
  int sd = si*2+d;
  int tid = threadIdx.x;
  int w = tid>>6, lane = tid&63;
  int l15 = lane&15, g16 = lane>>4;

  __shared__ int ord_s[MAXT];
  __shared__ alignas(16) signed char h8[2][DD];

  ord_s[tid] = order[a*MAXT + tid];
  if (tid < DD) h8[0][tid] = 0;

  int cnt = cnteff[2*a], eff = cnteff[2*a+1];

  int c0 = w*32 + l15, c1 = c0 + 16;
  float bn0 = bhh[sd*G3 + 2*DD + c0];
  float bn1 = bhh[sd*G3 + 2*DD + c1];
  const float ISQ = 1.f/(127.f*127.f);
  float sr0 = cm[sd*G3 +        c0]*ISQ;
  float sr1 = cm[sd*G3 +        c1]*ISQ;
  float sz0 = cm[sd*G3 + 256 +  c0]*ISQ;
  float sz1 = cm[sd*G3 + 256 +  c1]*ISQ;
  float sn0 = cm[sd*G3 + 512 +  c0]*ISQ;
  float sn1 = cm[sd*G3 + 512 +  c1]*ISQ;

  // B fragments: 24 x v4i = 96 dwords resident
  v4i bf[6][4];
  {
    const v4i* wp = whhB8 + (((size_t)sd*8 + w)*64 + lane)*24;
    #pragma unroll
    for (int nt=0;nt<6;++nt)
      #pragma unroll
      for (int q=0;q<4;++q)
        bf[nt][q] = wp[nt*4+q];
  }

  const uint4* Eb = reinterpret_cast<const uint4*>(E) + (size_t)sd*NNP*128;
  int li = w*16 + l15;

  float h0 = 0.f, h1 = 0.f;
  uint4 gEven, gOdd;
  {
    int idx0 = d ? (eff-1) : 0;
    int n0 = (idx0 < cnt) ? ord_s[idx0] : NN;
    gEven = Eb[(size_t)n0*128 + li];
  }
  __syncthreads();

  for (int t=0;t<eff;++t){
    int p = t & 1;
    // prefetch for t+1, issued before the MFMA phase so its latency is covered
    if (t+1 < eff){
      int idx1 = d ? (eff-2-t) : (t+1);
      int n1 = (idx1 < cnt) ? ord_s[idx1] : NN;
      if (p==0) gOdd  = Eb[(size_t)n1*128 + li];
      else      gEven = Eb[(size_t)n1*128 + li];
    }
    v4i acc0={0,0,0,0}, acc1={0,0,0,0}, acc2={0,0,0,0};
    v4i acc3={0,0,0,0}, acc4={0,0,0,0}, acc5={0,0,0,0};
    #pragma unroll
    for (int q=0;q<4;++q){
      v4i af = *reinterpret_cast<const v4i*>(&h8[p][64*q + 16*g16]);
      acc0 = __builtin_amdgcn_mfma_i32_16x16x64_i8(af, bf[0][q], acc0, 0,0,0);
      acc1 = __builtin_amdgcn_mfma_i32_16x16x64_i8(af, bf[1][q], acc1, 0,0,0);
      acc2 = __builtin_amdgcn_mfma_i32_16x16x64_i8(af, bf[2][q], acc2, 0,0,0);
      acc3 = __builtin_amdgcn_mfma_i32_16x16x64_i8(af, bf[3][q], acc3, 0,0,0);
      acc4 = __builtin_amdgcn_mfma_i32_16x16x64_i8(af, bf[4][q], acc4, 0,0,0);
      acc5 = __builtin_amdgcn_mfma_i32_16x16x64_i8(af, bf[5][q], acc5, 0,0,0);
    }
    v8h ev = __builtin_bit_cast(v8h, (p==0) ? gEven : gOdd);
    float yr0 = (float)acc0[0]*sr0;
    float yr1 = (float)acc1[0]*sr1;
    float yz0 = (float)acc2[0]*sz0;
    float yz1 = (float)acc3[0]*sz1;
    float yn0 = (float)acc4[0]*sn0 + bn0;
    float yn1 = (float)acc5[0]*sn1 + bn1;
    float r0 = sigf((float)ev[0] + yr0);
    float z0 = sigf((float)ev[1] + yz0);
    float n0v = tanhf_fast((float)ev[2] + r0*yn0);
    h0 = z0*(h0 - n0v) + n0v;
    float r1 = sigf((float)ev[3] + yr1);
    float z1 = sigf((float)ev[4] + yz1);
    float n1v = tanhf_fast((float)ev[5] + r1*yn1);
    h1 = z1*(h1 - n1v) + n1v;
    if (g16 == 0)      h8[p^1][c0] = (signed char)(int)rintf(h0*127.f);
    else if (g16 == 1) h8[p^1][c1] = (signed char)(int)rintf(h1*127.f);
    __syncthreads();
  }
  if (g16 == 0)      hout[(size_t)(2*a+d)*DD + c0] = h0;
  else if (g16 == 1) hout[(size_t)(2*a+d)*DD + c1] = h1;
}

// ---------------- MLP + head ----------------
__global__ __launch_bounds__(256) void mlp_kernel(const float* __restrict__ hout, const float* __restrict__ abn,
                           const float* __restrict__ anchors, const float* __restrict__ audio_len,
                           const float* __restrict__ w1T, const float* __restrict__ w2T,
                           const float* __restrict__ w3T,
                           const float* __restrict__ sw0, const float* __restrict__ ew0,
                           const float* __restrict__ sw1, const float* __restrict__ ew1,
                           const float* __restrict__ sw2, const float* __restrict__ ew2,
                           float* __restrict__ out){
  int a = blockIdx.x, tid = threadIdx.x;
  int si = scale_of(a);
  int il = a - off_of(si);
  float s = anchors[2*a], e = anchors[2*a+1];
  float al = audio_len[0];
  __shared__ float feat[520];
  __shared__ float h1[256], h2[256], o[PW3];
  feat[tid]    = hout[(size_t)(2*a+0)*DD + tid];
  feat[DD+tid] = hout[(size_t)(2*a+1)*DD + tid];
  if (tid==0){
    feat[512]=abn[il];
    feat[513]=(s+e)*0.5f/al;
    feat[514]=(e-s)/al;
    feat[515]=0.f; feat[516]=0.f; feat[517]=0.f; feat[518]=0.f; feat[519]=0.f;
  }
  __syncthreads();
  {
    const float* p1 = w1T + (size_t)si*520*256 + tid;
    float acc=0.f;
    #pragma unroll 4
    for (int k=0;k<519;++k) acc += feat[k]*p1[(size_t)k*256];
    h1[tid]=fmaxf(acc,0.f);
  }
  __syncthreads();
  {
    const float* p2 = w2T + (size_t)si*256*256 + tid;
    float acc=0.f;
    #pragma unroll 4
    for (int k=0;k<256;++k) acc += h1[k]*p2[(size_t)k*256];
    h2[tid]=fmaxf(acc,0.f);
  }
  __syncthreads();
  if (tid<PW3){
    const float* p3 = w3T + (size_t)si*256*PW3 + tid;
    float acc=0.f;
    #pragma unroll 4
    for (int k=0;k<256;++k) acc += h2[k]*p3[(size_t)k*PW3];
    o[tid]=acc;
  }
  __syncthreads();
  if (tid==0){
    int b = (si==1)?60:80;
    const float* sw = (si==0)?sw0:((si==1)?sw1:sw2);
    const float* ew = (si==0)?ew0:((si==1)?ew1:ew2);
    float m=-1e30f; for (int i=0;i<b;++i) m=fmaxf(m,o[i]);
    float se=0.f, wsum=0.f;
    for (int i=0;i<b;++i){ float t=expf(o[i]-m); se+=t; wsum+=t*sw[i]; }
    float so = wsum/se;
    m=-1e30f; for (int i=0;i<b;++i) m=fmaxf(m,o[b+i]);
    se=0.f; wsum=0.f;
    for (int i=0;i<b;++i){ float t=expf(o[b+i]-m); se+=t; wsum+=t*ew[i]; }
    float eo = wsum/se;
    out[2*a]   = fminf(fmaxf(s+so,0.f),al);
    out[2*a+1] = fminf(fmaxf(e+eo,0.f),al);
    out[140+a] = o[2*b];
    for (int c2=0;c2<4;++c2) out[210+4*a+c2] = o[2*b+1+c2];
  }
}

extern "C" void kernel_launch(void* const* d_in, const int* in_sizes, int n_in,
                              void* d_out, int out_size, void* d_ws, size_t ws_size,
                              hipStream_t stream){
  const float* emb   = (const float*)d_in[0];
  const float* tpin  = (const float*)d_in[1];
  const float* npred = (const float*)d_in[2];
  const float* alen  = (const float*)d_in[3];
  const float* anch  = (const float*)d_in[4];
  const float* wih   = (const float*)d_in[5];
  const float* whh   = (const float*)d_in[6];
  const float* bih   = (const float*)d_in[7];
  const float* bhh   = (const float*)d_in[8];
  const float* w1    = (const float*)d_in[9];
  const float* w2    = (const float*)d_in[10];
  const float* w30   = (const float*)d_in[11];
  const float* w31   = (const float*)d_in[12];
  const float* w32   = (const float*)d_in[13];
  const float* sw0   = (const float*)d_in[14];
  const float* ew0   = (const float*)d_in[15];
  const float* sw1   = (const float*)d_in[16];
  const float* ew1   = (const float*)d_in[17];
  const float* sw2   = (const float*)d_in[18];
  const float* ew2   = (const float*)d_in[19];

  char* ws = (char*)d_ws;
  size_t off = 0;
  auto take = [&](size_t bytes)->char*{
    char* p = ws + off;
    off = (off + bytes + 255) & ~(size_t)255;
    return p;
  };
  float* abn    = (float*)take((size_t)NN*4);
  int*   order_ = (int*)  take((size_t)NA*MAXT*4);
  int*   cnteff = (int*)  take((size_t)NA*2*4);
  float* qs     = (float*)take(16*4);
  float* cm     = (float*)take((size_t)6*G3*4);
  v4i*   whhB8  = (v4i*)  take((size_t)6*8*64*24*16);
  _Float16* E   = (_Float16*)take((size_t)6*NNP*1024*2);
  float* hout   = (float*)take((size_t)NA*2*DD*4);
  float* w1T    = (float*)take((size_t)3*520*256*4);
  float* w2T    = (float*)take((size_t)3*256*256*4);
  float* w3T    = (float*)take((size_t)3*256*PW3*4);
  (void)ws_size; (void)in_sizes; (void)n_in; (void)out_size;

  prep_kernel<<<dim3(119), dim3(256), 0, stream>>>(npred, tpin, alen, anch, whh, bih, bhh,
                                                   w1, w2, w30, w31, w32,
                                                   abn, order_, cnteff, qs, cm, E);
  e_gemm<<<dim3(16,12,6), dim3(256), 0, stream>>>(emb, wih, bih, bhh, E);
  {
    const int NT = 3*520*256 + 3*256*256 + 3*256*PW3;     // 731136
    int nb = 288 + (NT+255)/256;
    quant_kernel<<<dim3(nb), dim3(256), 0, stream>>>(whh, cm, w1, w2, w30, w31, w32, qs,
                                                     (uint4*)whhB8, w1T, w2T, w3T);
  }
  gru_kernel<<<dim3(NA*2), dim3(512), 0, stream>>>(E, whhB8, bhh, cm, order_, cnteff, hout);
  mlp_kernel<<<dim3(NA), dim3(256), 0, stream>>>(hout, abn, anch, alen, w1T, w2T, w3T,
                                                 sw0, ew0, sw1, ew1, sw2, ew2, (float*)d_out);
}

// Round 8
// 462.375 us; speedup vs baseline: 1.5772x; 1.2971x over previous
//
#include <hip/hip_runtime.h>
#include <math.h>

#define NN 1024
#define NNP 1025
#define DD 256
#define CC 5
#define G3 768
#define MAXT 512
#define NA 70
#define PW3 176

typedef _Float16 v4h __attribute__((ext_vector_type(4)));
typedef int v4i __attribute__((ext_vector_type(4)));

__device__ __forceinline__ int scale_of(int a){ return (a<15)?0:((a<55)?1:2); }
__device__ __forceinline__ int off_of(int s){ return (s==0)?0:((s==1)?15:55); }

__device__ __forceinline__ float sigf(float x){ return __fdividef(1.f, 1.f + __expf(-x)); }
__device__ __forceinline__ float tanhf_fast(float x){ return 1.f - __fdividef(2.f, __expf(2.f*x) + 1.f); }

__global__ void init_qs(unsigned int* __restrict__ qsb){
  if (threadIdx.x < 16) qsb[threadIdx.x] = 0u;
}

// ---------------- PREP mega-kernel ----------------
// blocks 0..3      : abn = softmax(node_pred)[:,0]
// blocks 4..73     : per-anchor stable gather (order/cnteff)
// blocks 74..217   : 9 matrices x 16 stripes absmax -> atomicMax(qs_bits)
// blocks 218..1369 : whh per-column absmax (4 rows/block, 1 wave/row, coalesced)
// blocks 1370..1387: fill fake bias row NN of E (fp16, [cell][slot] layout)
__global__ __launch_bounds__(256) void prep_kernel(
    const float* __restrict__ node_pred, const float* __restrict__ tp_in,
    const float* __restrict__ audio_len, const float* __restrict__ anchors,
    const float* __restrict__ whh,
    const float* __restrict__ bih, const float* __restrict__ bhh,
    const float* __restrict__ w1, const float* __restrict__ w2,
    const float* __restrict__ w30, const float* __restrict__ w31, const float* __restrict__ w32,
    float* __restrict__ abn, int* __restrict__ order, int* __restrict__ cnteff,
    unsigned int* __restrict__ qsb, float* __restrict__ cm, _Float16* __restrict__ E){
  int b = blockIdx.x, tid = threadIdx.x;
  if (b < 4){
    int i = b*256 + tid;
    float pv[CC]; float m = -1e30f;
    for (int c=0;c<CC;++c){ pv[c]=node_pred[i*CC+c]; m=fmaxf(m,pv[c]); }
    float s=0.f;
    for (int c=0;c<CC;++c) s += expf(pv[c]-m);
    abn[i] = expf(pv[0]-m)/s;
  } else if (b < 74){
    if (tid >= 64) return;
    int a = b-4; int lane = tid;
    float al = audio_len[0];
    float s = anchors[2*a], e = anchors[2*a+1];
    int* ord = order + a*MAXT;
    int cnt = 0;
    for (int base=0; base<NN; base+=64){
      float tp = tp_in[base+lane]*al;
      bool msk = (tp>=s)&&(tp<=e);
      unsigned long long bal = __ballot(msk);
      int off = (int)__popcll(bal & ((1ull<<lane)-1ull));
      if (msk && (cnt+off)<MAXT) ord[cnt+off] = base+lane;
      cnt += (int)__popcll(bal);
    }
    if (lane==0){ int c = cnt<MAXT?cnt:MAXT; cnteff[2*a]=c; cnteff[2*a+1]=(c>0)?c:1; }
  } else if (b < 218){
    int m = (b-74)>>4, s = (b-74)&15;
    const float* p; int n;
    if (m<3){ p = w1 + (size_t)m*256*519; n = 256*519; }
    else if (m<6){ p = w2 + (size_t)(m-3)*256*256; n = 256*256; }
    else { p = (m==6)?w30:((m==7)?w31:w32); n = ((m==7)?125:165)*256; }
    float mx = 0.f;
    for (int i = s*256+tid; i<n; i += 16*256) mx = fmaxf(mx, fabsf(p[i]));
    #pragma unroll
    for (int sh=1; sh<64; sh<<=1) mx = fmaxf(mx, __shfl_xor(mx, sh));
    if ((tid&63)==0) atomicMax(&qsb[m], __float_as_uint(mx));
  } else if (b < 1370){
    int row = (b-218)*4 + (tid>>6);
    int lane = tid&63;
    float4 v = reinterpret_cast<const float4*>(whh)[(size_t)row*64 + lane];
    float mx = fmaxf(fmaxf(fabsf(v.x),fabsf(v.y)), fmaxf(fabsf(v.z),fabsf(v.w)));
    #pragma unroll
    for (int sh=1; sh<64; sh<<=1) mx = fmaxf(mx, __shfl_xor(mx, sh));
    if (lane==0) cm[row] = fmaxf(mx, 1e-12f);
  } else {
    int i = (b-1370)*256 + tid;           // 6*256*3 = 4608
    if (i >= 4608) return;
    int gt = i % 3; int c = (i/3)&255; int sd = i/768;
    int j = gt*256 + c;
    float v = bih[sd*G3+j] + ((gt<2)? bhh[sd*G3+j] : 0.f);
    E[((size_t)(sd*NNP + NN))*1024 + c*4 + gt] = (_Float16)v;
  }
}

// ---------------- QUANT kernel ----------------
// blocks 0..287      : whhB8 int8 MFMA B-fragments (per-column scale cm)
// blocks 288..1055   : w1T (row-per-block, coalesced reads)
// blocks 1056..1823  : w2T
// blocks 1824..2351  : w3T
__global__ __launch_bounds__(256) void quant_kernel(
    const float* __restrict__ whh, const float* __restrict__ cm,
    const float* __restrict__ w1, const float* __restrict__ w2,
    const float* __restrict__ w30, const float* __restrict__ w31, const float* __restrict__ w32,
    const unsigned int* __restrict__ qsb,
    uint4* __restrict__ whhB8, float* __restrict__ w1T, float* __restrict__ w2T, float* __restrict__ w3T){
  int b = blockIdx.x, tid = threadIdx.x;
  if (b < 288){
    int i = b*256 + tid;                  // < 6*8*64*24 = 73728
    int q    = i & 3;
    int nt   = (i>>2) % 6;
    int lane = (i/24) & 63;
    int wv   = (i/1536) & 7;
    int sd   = i/12288;
    int gt = nt>>1, half = nt&1;
    int j = gt*256 + wv*32 + half*16 + (lane&15);
    int kbase = 64*q + 16*(lane>>4);
    float inv = 127.f/cm[sd*G3 + j];
    const float* src = whh + ((size_t)sd*G3 + j)*DD + kbase;
    unsigned int dw[4];
    #pragma unroll
    for (int d2=0; d2<4; ++d2){
      unsigned int acc = 0;
      #pragma unroll
      for (int e2=0; e2<4; ++e2){
        float qv = rintf(src[4*d2+e2]*inv);
        qv = fminf(fmaxf(qv,-127.f),127.f);
        int iq = (int)qv;
        acc |= ((unsigned int)(iq & 255)) << (8*e2);
      }
      dw[d2] = acc;
    }
    uint4 v; v.x=dw[0]; v.y=dw[1]; v.z=dw[2]; v.w=dw[3];
    whhB8[i] = v;
  } else if (b < 1056){
    int row = b-288; int si = row>>8; int j = row&255;
    float sc = fmaxf(__uint_as_float(qsb[si])/127.f, 1e-8f);
    const float* src = w1 + ((size_t)si*256 + j)*519;
    #pragma unroll
    for (int it=0; it<3; ++it){
      int k = it*256 + tid;
      if (k >= 520) break;
      float v = 0.f;
      if (k < 519){
        float q = rintf(src[k]/sc);
        q = fminf(fmaxf(q,-128.f),127.f);
        v = q*sc;
      }
      w1T[((size_t)si*520 + k)*256 + j] = v;
    }
  } else if (b < 1824){
    int row = b-1056; int si = row>>8; int j = row&255;
    float sc = fmaxf(__uint_as_float(qsb[3+si])/127.f, 1e-8f);
    const float* src = w2 + ((size_t)si*256 + j)*256;
    float q = rintf(src[tid]/sc);
    q = fminf(fmaxf(q,-128.f),127.f);
    w2T[((size_t)si*256 + tid)*256 + j] = q*sc;
  } else {
    int row = b-1824; int si = row/PW3; int j = row%PW3;
    int nout = (si==1)?125:165;
    const float* w3 = (si==0)?w30:((si==1)?w31:w32);
    float v = 0.f;
    if (j < nout){
      float sc = fmaxf(__uint_as_float(qsb[6+si])/127.f, 1e-8f);
      float q = rintf(w3[(size_t)j*256 + tid]/sc);
      q = fminf(fmaxf(q,-128.f),127.f);
      v = q*sc;
    }
    w3T[((size_t)si*256 + tid)*PW3 + j] = v;
  }
}

// ---------------- E-GEMM (fp16 out, [cell][slot] layout, biases folded) ----------------
__global__ __launch_bounds__(256) void e_gemm(const float* __restrict__ emb, const float* __restrict__ wih,
                       const float* __restrict__ bih, const float* __restrict__ bhh,
                       _Float16* __restrict__ E){
  int sd = blockIdx.z;
  int row0 = blockIdx.x*64, col0 = blockIdx.y*64;
  const float* W = wih + (size_t)sd*G3*DD;
  __shared__ float As[64][65];
  __shared__ float Bs[64][65];
  int tid = threadIdx.x;
  int tr = tid>>4, tc = tid&15;
  float acc[4][4] = {};
  for (int kb=0; kb<4; ++kb){
    for (int i=0;i<4;++i){
      int e4 = i*256 + tid;
      int rr = e4>>4, qq = e4&15;
      float4 av = reinterpret_cast<const float4*>(emb)[ (size_t)(row0+rr)*64 + kb*16 + qq ];
      As[rr][qq*4+0]=av.x; As[rr][qq*4+1]=av.y; As[rr][qq*4+2]=av.z; As[rr][qq*4+3]=av.w;
      float4 bv = reinterpret_cast<const float4*>(W)[ (size_t)(col0+rr)*64 + kb*16 + qq ];
      Bs[rr][qq*4+0]=bv.x; Bs[rr][qq*4+1]=bv.y; Bs[rr][qq*4+2]=bv.z; Bs[rr][qq*4+3]=bv.w;
    }
    __syncthreads();
    for (int k=0;k<64;++k){
      float a0[4], b0[4];
      #pragma unroll
      for (int i=0;i<4;++i) a0[i]=As[tr*4+i][k];
      #pragma unroll
      for (int j=0;j<4;++j) b0[j]=Bs[tc*4+j][k];
      #pragma unroll
      for (int i=0;i<4;++i)
        #pragma unroll
        for (int j=0;j<4;++j)
          acc[i][j] += a0[i]*b0[j];
    }
    __syncthreads();
  }
  for (int i=0;i<4;++i){
    int row = row0 + tr*4 + i;
    for (int j=0;j<4;++j){
      int col = col0 + tc*4 + j;
      int gt = col>>8; int c = col&255;
      float val = acc[i][j] + bih[sd*G3+col] + ((gt<2)? bhh[sd*G3+col] : 0.f);
      E[((size_t)(sd*NNP + row))*1024 + c*4 + gt] = (_Float16)val;
    }
  }
}

// ---------------- GRU: int8 MFMA 16x16x64, 1 cell/lane, 8B/lane E loads ----------------
__global__ __launch_bounds__(512, 2) void gru_kernel(
                           const _Float16* __restrict__ E, const v4i* __restrict__ whhB8,
                           const float* __restrict__ bhh, const float* __restrict__ cm,
                           const int* __restrict__ order, const int* __restrict__ cnteff,
                           float* __restrict__ hout){
  int a = blockIdx.x>>1, d = blockIdx.x&1;
  int si = scale_of(a);
  int sd = si*2+d;
  int tid = threadIdx.x;
  int w = tid>>6, lane = tid&63;
  int g16 = lane>>4;
  int ct = g16 & 1;

  __shared__ int ord_s[MAXT];
  __shared__ alignas(16) signed char h8[2][DD];

  ord_s[tid] = order[a*MAXT + tid];
  if (tid < DD) h8[0][tid] = 0;

  int cnt = cnteff[2*a], eff = cnteff[2*a+1];

  int c = w*32 + (lane&31);                 // this lane's cell
  float bn = bhh[sd*G3 + 2*DD + c];
  const float ISQ = 1.f/(127.f*127.f);
  float sr = cm[sd*G3 +        c]*ISQ;
  float sz = cm[sd*G3 + 256 +  c]*ISQ;
  float sn = cm[sd*G3 + 512 +  c]*ISQ;

  // B fragments: 24 x v4i = 96 dwords resident
  v4i bf[6][4];
  {
    const v4i* wp = whhB8 + (((size_t)sd*8 + w)*64 + lane)*24;
    #pragma unroll
    for (int nt=0;nt<6;++nt)
      #pragma unroll
      for (int q=0;q<4;++q)
        bf[nt][q] = wp[nt*4+q];
  }

  const uint2* Eb = reinterpret_cast<const uint2*>(E) + (size_t)sd*NNP*256;
  // lane's 8B slot: (node*256 + c) uint2's

  float h = 0.f;
  uint2 gEven, gOdd;
  {
    int idx0 = d ? (eff-1) : 0;
    int n0 = (idx0 < cnt) ? ord_s[idx0] : NN;
    gEven = Eb[(size_t)n0*256 + c];
  }
  __syncthreads();

  for (int t=0;t<eff;++t){
    int p = t & 1;
    if (t+1 < eff){
      int idx1 = d ? (eff-2-t) : (t+1);
      int n1 = (idx1 < cnt) ? ord_s[idx1] : NN;
      if (p==0) gOdd  = Eb[(size_t)n1*256 + c];
      else      gEven = Eb[(size_t)n1*256 + c];
    }
    v4i acc0={0,0,0,0}, acc1={0,0,0,0}, acc2={0,0,0,0};
    v4i acc3={0,0,0,0}, acc4={0,0,0,0}, acc5={0,0,0,0};
    #pragma unroll
    for (int q=0;q<4;++q){
      v4i af = *reinterpret_cast<const v4i*>(&h8[p][64*q + 16*g16]);
      acc0 = __builtin_amdgcn_mfma_i32_16x16x64_i8(af, bf[0][q], acc0, 0,0,0);
      acc1 = __builtin_amdgcn_mfma_i32_16x16x64_i8(af, bf[1][q], acc1, 0,0,0);
      acc2 = __builtin_amdgcn_mfma_i32_16x16x64_i8(af, bf[2][q], acc2, 0,0,0);
      acc3 = __builtin_amdgcn_mfma_i32_16x16x64_i8(af, bf[3][q], acc3, 0,0,0);
      acc4 = __builtin_amdgcn_mfma_i32_16x16x64_i8(af, bf[4][q], acc4, 0,0,0);
      acc5 = __builtin_amdgcn_mfma_i32_16x16x64_i8(af, bf[5][q], acc5, 0,0,0);
    }
    v4h ev = __builtin_bit_cast(v4h, (p==0) ? gEven : gOdd);
    int ir  = (ct==0) ? acc0[0] : acc1[0];
    int iz  = (ct==0) ? acc2[0] : acc3[0];
    int inn = (ct==0) ? acc4[0] : acc5[0];
    float r  = sigf((float)ev[0] + (float)ir*sr);
    float z  = sigf((float)ev[1] + (float)iz*sz);
    float nv = tanhf_fast((float)ev[2] + r*((float)inn*sn + bn));
    h = z*(h - nv) + nv;
    if (lane < 32) h8[p^1][c] = (signed char)(int)rintf(h*127.f);
    __syncthreads();
  }
  if (lane < 32) hout[(size_t)(2*a+d)*DD + c] = h;
}

// ---------------- MLP + head ----------------
__global__ __launch_bounds__(256) void mlp_kernel(const float* __restrict__ hout, const float* __restrict__ abn,
                           const float* __restrict__ anchors, const float* __restrict__ audio_len,
                           const float* __restrict__ w1T, const float* __restrict__ w2T,
                           const float* __restrict__ w3T,
                           const float* __restrict__ sw0, const float* __restrict__ ew0,
                           const float* __restrict__ sw1, const float* __restrict__ ew1,
                           const float* __restrict__ sw2, const float* __restrict__ ew2,
                           float* __restrict__ out){
  int a = blockIdx.x, tid = threadIdx.x;
  int si = scale_of(a);
  int il = a - off_of(si);
  float s = anchors[2*a], e = anchors[2*a+1];
  float al = audio_len[0];
  __shared__ float feat[520];
  __shared__ float h1[256], h2[256], o[PW3];
  feat[tid]    = hout[(size_t)(2*a+0)*DD + tid];
  feat[DD+tid] = hout[(size_t)(2*a+1)*DD + tid];
  if (tid==0){
    feat[512]=abn[il];
    feat[513]=(s+e)*0.5f/al;
    feat[514]=(e-s)/al;
    feat[515]=0.f; feat[516]=0.f; feat[517]=0.f; feat[518]=0.f; feat[519]=0.f;
  }
  __syncthreads();
  {
    const float* p1 = w1T + (size_t)si*520*256 + tid;
    float acc=0.f;
    #pragma unroll 4
    for (int k=0;k<519;++k) acc += feat[k]*p1[(size_t)k*256];
    h1[tid]=fmaxf(acc,0.f);
  }
  __syncthreads();
  {
    const float* p2 = w2T + (size_t)si*256*256 + tid;
    float acc=0.f;
    #pragma unroll 4
    for (int k=0;k<256;++k) acc += h1[k]*p2[(size_t)k*256];
    h2[tid]=fmaxf(acc,0.f);
  }
  __syncthreads();
  if (tid<PW3){
    const float* p3 = w3T + (size_t)si*256*PW3 + tid;
    float acc=0.f;
    #pragma unroll 4
    for (int k=0;k<256;++k) acc += h2[k]*p3[(size_t)k*PW3];
    o[tid]=acc;
  }
  __syncthreads();
  if (tid==0){
    int b = (si==1)?60:80;
    const float* sw = (si==0)?sw0:((si==1)?sw1:sw2);
    const float* ew = (si==0)?ew0:((si==1)?ew1:ew2);
    float m=-1e30f; for (int i=0;i<b;++i) m=fmaxf(m,o[i]);
    float se=0.f, wsum=0.f;
    for (int i=0;i<b;++i){ float t=expf(o[i]-m); se+=t; wsum+=t*sw[i]; }
    float so = wsum/se;
    m=-1e30f; for (int i=0;i<b;++i) m=fmaxf(m,o[b+i]);
    se=0.f; wsum=0.f;
    for (int i=0;i<b;++i){ float t=expf(o[b+i]-m); se+=t; wsum+=t*ew[i]; }
    float eo = wsum/se;
    out[2*a]   = fminf(fmaxf(s+so,0.f),al);
    out[2*a+1] = fminf(fmaxf(e+eo,0.f),al);
    out[140+a] = o[2*b];
    for (int c2=0;c2<4;++c2) out[210+4*a+c2] = o[2*b+1+c2];
  }
}

extern "C" void kernel_launch(void* const* d_in, const int* in_sizes, int n_in,
                              void* d_out, int out_size, void* d_ws, size_t ws_size,
                              hipStream_t stream){
  const float* emb   = (const float*)d_in[0];
  const float* tpin  = (const float*)d_in[1];
  const float* npred = (const float*)d_in[2];
  const float* alen  = (const float*)d_in[3];
  const float* anch  = (const float*)d_in[4];
  const float* wih   = (const float*)d_in[5];
  const float* whh   = (const float*)d_in[6];
  const float* bih   = (const float*)d_in[7];
  const float* bhh   = (const float*)d_in[8];
  const float* w1    = (const float*)d_in[9];
  const float* w2    = (const float*)d_in[10];
  const float* w30   = (const float*)d_in[11];
  const float* w31   = (const float*)d_in[12];
  const float* w32   = (const float*)d_in[13];
  const float* sw0   = (const float*)d_in[14];
  const float* ew0   = (const float*)d_in[15];
  const float* sw1   = (const float*)d_in[16];
  const float* ew1   = (const float*)d_in[17];
  const float* sw2   = (const float*)d_in[18];
  const float* ew2   = (const float*)d_in[19];

  char* ws = (char*)d_ws;
  size_t off = 0;
  auto take = [&](size_t bytes)->char*{
    char* p = ws + off;
    off = (off + bytes + 255) & ~(size_t)255;
    return p;
  };
  float* abn    = (float*)take((size_t)NN*4);
  int*   order_ = (int*)  take((size_t)NA*MAXT*4);
  int*   cnteff = (int*)  take((size_t)NA*2*4);
  unsigned int* qsb = (unsigned int*)take(16*4);
  float* cm     = (float*)take((size_t)6*G3*4);
  v4i*   whhB8  = (v4i*)  take((size_t)6*8*64*24*16);
  _Float16* E   = (_Float16*)take((size_t)6*NNP*1024*2);
  float* hout   = (float*)take((size_t)NA*2*DD*4);
  float* w1T    = (float*)take((size_t)3*520*256*4);
  float* w2T    = (float*)take((size_t)3*256*256*4);
  float* w3T    = (float*)take((size_t)3*256*PW3*4);
  (void)ws_size; (void)in_sizes; (void)n_in; (void)out_size;

  init_qs<<<dim3(1), dim3(64), 0, stream>>>(qsb);
  prep_kernel<<<dim3(1388), dim3(256), 0, stream>>>(npred, tpin, alen, anch, whh, bih, bhh,
                                                    w1, w2, w30, w31, w32,
                                                    abn, order_, cnteff, qsb, cm, E);
  e_gemm<<<dim3(16,12,6), dim3(256), 0, stream>>>(emb, wih, bih, bhh, E);
  quant_kernel<<<dim3(2352), dim3(256), 0, stream>>>(whh, cm, w1, w2, w30, w31, w32, qsb,
                                                     (uint4*)whhB8, w1T, w2T, w3T);
  gru_kernel<<<dim3(NA*2), dim3(512), 0, stream>>>(E, whhB8, bhh, cm, order_, cnteff, hout);
  mlp_kernel<<<dim3(NA), dim3(256), 0, stream>>>(hout, abn, anch, alen, w1T, w2T, w3T,
                                                 sw0, ew0, sw1, ew1, sw2, ew2, (float*)d_out);
}